// Round 5
// baseline (38.681 us; speedup 1.0000x reference)
//
#include <hip/hip_runtime.h>
#include <math.h>

// YOLO box decode: x[B=32, A*(NC+5)=255, G=52, G=52] f32 ->
// out[B, A*G*G=8112, 85] f32  (+ trailing scalar 0 from the tuple return).
//
// R1: TILE 64 (7 blocks/CU), float4 reads, native exp.      47.2 -> 37.6 us
// R3/R4: unrolled 6-deep load/store phases (MLP), NT stores. 37.6 -> 35.7 us
// R5: TILE=52 divides 2704 exactly -> no tail blocks; LDS 17.68KB ->
//     8 blocks/CU * 4 waves = 32 waves (100% occupancy cap, was 7blk/87%
//     cap with 55% measured). Load phase uses 13/16 lanes (issue slots
//     only -- VALUBusy was 20%, plenty of headroom).

#define NB    32
#define NA    3
#define NCH   85
#define GG    52
#define CELLS (GG * GG)          // 2704
#define TILE  52                 // cells per block; 2704/52 = 52 tiles exact
#define NTILES (CELLS / TILE)    // 52
#define STRIDEF 8.0f

typedef float f32x4 __attribute__((ext_vector_type(4)));

__device__ __forceinline__ float sigm(float v) {
    return __fdividef(1.0f, 1.0f + __expf(-v));
}

__global__ __launch_bounds__(256, 8) void yolo_decode(const float* __restrict__ x,
                                                      float* __restrict__ out,
                                                      long long out_size) {
    __shared__ __align__(16) float lds[TILE * NCH];   // 17.68 KB -> 8 blocks/CU

    const int tile = blockIdx.x;
    const int a    = blockIdx.y;
    const int b    = blockIdx.z;
    const int cell0 = tile * TILE;

    const int lane = threadIdx.x & 63;
    const int wv   = threadIdx.x >> 6;                // 0..3

    const float aw = (a == 0) ? 10.0f : (a == 1) ? 16.0f : 33.0f;
    const float ah = (a == 0) ? 13.0f : (a == 1) ? 30.0f : 23.0f;

    // fold the tuple's trailing scalar 0 into this kernel (no extra launch)
    const long long MAIN = (long long)NB * NA * CELLS * NCH;
    if (tile == 0 && a == 0 && b == 0 && threadIdx.x == 0 && out_size > MAIN) {
        for (long long i = MAIN; i < out_size; ++i) out[i] = 0.0f;
    }

    // input base for this (b, a), at cell0
    const float* xb = x + ((size_t)(b * NA + a) * NCH) * CELLS + cell0;

    const int grp   = lane >> 4;                      // 0..3: channel sub-group
    const int c4    = (lane & 15) * 4;                // local cell (x4), 0..60
    const int start = wv * 4 + grp;                   // first channel: 0..15

    if (c4 < TILE) {                                  // lanes 0..12 of 16 active
        float gx[4], gy[4];
        #pragma unroll
        for (int j = 0; j < 4; ++j) {
            const int cell = cell0 + c4 + j;
            gx[j] = (float)(cell % GG);
            gy[j] = (float)(cell / GG);
        }

        // channels: start + 16k. k=0..4 always valid (start<=15 -> ch<=79);
        // k=5 valid iff start<5 (ch=start+80<85).
        // Issue ALL loads first -> 5-6 outstanding global loads per thread.
        f32x4 v[6];
        #pragma unroll
        for (int k = 0; k < 5; ++k)
            v[k] = *(const f32x4*)(xb + (size_t)(start + 16 * k) * CELLS + c4);
        const bool has6 = (start < 5);
        if (has6)
            v[5] = *(const f32x4*)(xb + (size_t)(start + 80) * CELLS + c4);

        // transform: only k==0 can hit the 4 special channels (ch=start<16)
        {
            float r[4] = {v[0].x, v[0].y, v[0].z, v[0].w};
            if (start == 0) {
                #pragma unroll
                for (int j = 0; j < 4; ++j) r[j] = (sigm(r[j]) + gx[j]) * STRIDEF;
            } else if (start == 1) {
                #pragma unroll
                for (int j = 0; j < 4; ++j) r[j] = (sigm(r[j]) + gy[j]) * STRIDEF;
            } else if (start == 2) {
                #pragma unroll
                for (int j = 0; j < 4; ++j) r[j] = __expf(r[j]) * aw;
            } else if (start == 3) {
                #pragma unroll
                for (int j = 0; j < 4; ++j) r[j] = __expf(r[j]) * ah;
            } else {
                #pragma unroll
                for (int j = 0; j < 4; ++j) r[j] = sigm(r[j]);
            }
            #pragma unroll
            for (int j = 0; j < 4; ++j) lds[(c4 + j) * NCH + start] = r[j];
        }
        #pragma unroll
        for (int k = 1; k < 5; ++k) {
            const int ch = start + 16 * k;
            float r[4] = {v[k].x, v[k].y, v[k].z, v[k].w};
            #pragma unroll
            for (int j = 0; j < 4; ++j) lds[(c4 + j) * NCH + ch] = sigm(r[j]);
        }
        if (has6) {
            const int ch = start + 80;
            float r[4] = {v[5].x, v[5].y, v[5].z, v[5].w};
            #pragma unroll
            for (int j = 0; j < 4; ++j) lds[(c4 + j) * NCH + ch] = sigm(r[j]);
        }
    }
    __syncthreads();

    // coalesced float4 writeback, fully unrolled: issue all ds_reads, then
    // all nontemporal global stores. total4 = 52*85/4 = 1105 (exact, 16B-
    // aligned base: 52*85*4 = 17680 % 16 == 0).
    float* ob = out + ((size_t)((b * NA + a) * CELLS + cell0)) * NCH;
    const int total4 = (TILE * NCH) >> 2;             // 1105
    const f32x4* l4 = (const f32x4*)lds;
    f32x4* o4 = (f32x4*)ob;

    f32x4 t[5];
    #pragma unroll
    for (int k = 0; k < 5; ++k) {
        const int j = (int)threadIdx.x + 256 * k;
        if (j < total4) t[k] = l4[j];
    }
    #pragma unroll
    for (int k = 0; k < 5; ++k) {
        const int j = (int)threadIdx.x + 256 * k;
        if (j < total4) __builtin_nontemporal_store(t[k], &o4[j]);
    }
}

extern "C" void kernel_launch(void* const* d_in, const int* in_sizes, int n_in,
                              void* d_out, int out_size, void* d_ws, size_t ws_size,
                              hipStream_t stream) {
    const float* x = (const float*)d_in[0];
    float* out = (float*)d_out;

    dim3 grid(NTILES, NA, NB);      // 52 x 3 x 32 = 4992 blocks
    yolo_decode<<<grid, 256, 0, stream>>>(x, out, (long long)out_size);
}